// Round 3
// baseline (108.027 us; speedup 1.0000x reference)
//
#include <hip/hip_runtime.h>
#include <math.h>

// MGNO layer: B=2, N=4096, C=64, ORDER=4, COORD=2, K=8
#define NNODES 4096
#define KNN 8
// 2-D grid: 64x64 cells over [-4.5, 4.5]^2; edge cells absorb clamped points.
#define GX 64
#define NCELL (GX * GX)
#define BOX_LO (-4.5f)
#define CELL_INV (7.11111111f)   // GX / 9.0

__device__ __forceinline__ int binf(float v) {
    int k = (int)floorf((v - BOX_LO) * CELL_INV);
    return min(GX - 1, max(0, k));
}

__device__ __forceinline__ float cleanf(float v) {
    if (v != v) return 0.0f;
    return fminf(fmaxf(v, -1.0e6f), 1.0e6f);
}

__device__ __forceinline__ float gelu_tanh(float v) {
    float v3 = v * v * v;
    float t = tanhf(0.7978845608028654f * (v + 0.044715f * v3));
    return 0.5f * v * (1.0f + t);
}

__device__ __forceinline__ float wave_sum64(float v) {
    #pragma unroll
    for (int off = 32; off > 0; off >>= 1)
        v += __shfl_xor(v, off, 64);
    return v;
}

// readlane: wave-uniform SGPR broadcast of lane l's value (VALU pipe, not LDS).
__device__ __forceinline__ float rdl(float v, int l) {
    return __int_as_float(__builtin_amdgcn_readlane(__float_as_int(v), l));
}

// ---------------------------------------------------------------------------
// Kernel 0: prep. Blocks 0-1: clean pos, counting-sort into 64x64 cells
// (one block/batch). Blocks 2-7: transpose all weight matrices into ws so
// the GEMM kernels can stage per-lane-column b128 LDS layouts with coalesced
// global reads. Transposes run on otherwise-idle CUs (prep is 2 blocks).
// ---------------------------------------------------------------------------
__global__ __launch_bounds__(1024) void prep_kernel(
    const float* __restrict__ pos, float4* __restrict__ spk,
    int* __restrict__ boff,
    const float* __restrict__ mw,  const float* __restrict__ mW1,
    const float* __restrict__ mW2, const float* __restrict__ uW1,
    const float* __restrict__ uW2,
    float* __restrict__ uW1t, float* __restrict__ uW2t,
    float* __restrict__ mW2t, float* __restrict__ mWlt,
    float* __restrict__ mW1tA, float* __restrict__ mW1tB)
{
    __shared__ int cnt[NCELL];       // 16 KB; reused as scatter cursor
    __shared__ int wsum[16], wexcl[16];

    if (blockIdx.x >= 2) {
        // ---- weight transposes ----
        int tid = (blockIdx.x - 2) * 1024 + threadIdx.x;  // 0..6143
        const int STEP = 6 * 1024;
        // uW1t[j][i] = uW1[i][j]   (128x128)
        for (int g = tid; g < 128 * 128; g += STEP) {
            int j = g >> 7, i = g & 127;
            uW1t[g] = uW1[i * 128 + j];
        }
        // uW2t[j][h] = uW2[h][j]   (uW2 is 128x64 -> 64x128)
        for (int g = tid; g < 64 * 128; g += STEP) {
            int j = g >> 7, h = g & 127;
            uW2t[g] = uW2[h * 64 + j];
        }
        // mW2t[j][h] = mW2[h][j]   (64x64)
        for (int g = tid; g < 64 * 64; g += STEP) {
            int j = g >> 6, h = g & 63;
            mW2t[g] = mW2[h * 64 + j];
        }
        // mWlt[o][j][i] = W[i][j][o]  (W flat: (i*64+j)*5+o)
        for (int g = tid; g < 5 * 64 * 64; g += STEP) {
            int o = g >> 12, rem = g & 4095, j = rem >> 6, i = rem & 63;
            mWlt[g] = mw[(i * 64 + j) * 5 + o];
        }
        // mW1tA[j][i] = mW1[i][j]; mW1tB[j][i] = mW1[64+i][j]  (128x64 halves)
        for (int g = tid; g < 64 * 64; g += STEP) {
            int j = g >> 6, i = g & 63;
            mW1tA[g] = mW1[i * 64 + j];
            mW1tB[g] = mW1[(64 + i) * 64 + j];
        }
        return;
    }

    int b    = blockIdx.x;
    int t    = threadIdx.x;
    int wid  = t >> 6;
    int lane = t & 63;
    const float2* pb = (const float2*)(pos + (size_t)b * NNODES * 2);

    float qx[4], qy[4];
    int ck[4];
    #pragma unroll
    for (int s = 0; s < 4; ++s) cnt[t + s * 1024] = 0;
    __syncthreads();

    #pragma unroll
    for (int s = 0; s < 4; ++s) {
        float2 p = pb[t + s * 1024];
        qx[s] = cleanf(p.x); qy[s] = cleanf(p.y);
        ck[s] = binf(qy[s]) * GX + binf(qx[s]);
        atomicAdd(&cnt[ck[s]], 1);
    }
    __syncthreads();

    // exclusive prefix scan of cnt[4096]: 4 cells/thread + wave/block scan
    int c0 = cnt[4 * t], c1 = cnt[4 * t + 1], c2 = cnt[4 * t + 2], c3 = cnt[4 * t + 3];
    int s4 = c0 + c1 + c2 + c3;
    int sc = s4;
    #pragma unroll
    for (int off = 1; off < 64; off <<= 1) {
        int o = __shfl_up(sc, off, 64);
        if (lane >= off) sc += o;
    }
    if (lane == 63) wsum[wid] = sc;
    __syncthreads();
    if (t < 16) {
        int v = wsum[t];
        #pragma unroll
        for (int off = 1; off < 16; off <<= 1) {
            int o = __shfl_up(v, off, 64);
            if (t >= off) v += o;
        }
        wexcl[t] = v - wsum[t];
    }
    __syncthreads();
    int base = wexcl[wid] + (sc - s4);
    int* bofb = boff + b * (NCELL + 1);
    bofb[4 * t]     = base;
    bofb[4 * t + 1] = base + c0;
    bofb[4 * t + 2] = base + c0 + c1;
    bofb[4 * t + 3] = base + c0 + c1 + c2;
    if (t == 0) bofb[NCELL] = NNODES;
    cnt[4 * t]     = base;
    cnt[4 * t + 1] = base + c0;
    cnt[4 * t + 2] = base + c0 + c1;
    cnt[4 * t + 3] = base + c0 + c1 + c2;
    __syncthreads();

    #pragma unroll
    for (int s = 0; s < 4; ++s) {
        int p = atomicAdd(&cnt[ck[s]], 1);
        spk[(size_t)b * NNODES + p] =
            make_float4(qx[s], qy[s], __int_as_float(t + s * 1024), 0.0f);
    }
}

#define INSERT8(cur)                                                     \
    {                                                                    \
        unsigned long long c_ = (cur);                                   \
        _Pragma("unroll")                                                \
        for (int q_ = 0; q_ < 8; ++q_) {                                 \
            unsigned long long mn_ = (c_ < best[q_]) ? c_ : best[q_];    \
            c_ = (c_ < best[q_]) ? best[q_] : c_;                        \
            best[q_] = mn_;                                              \
        }                                                                \
    }

// ---------------------------------------------------------------------------
// Kernel 1: exact 8-NN via 2-D cell grid, one wave per query row. (unchanged)
// ---------------------------------------------------------------------------
__global__ __launch_bounds__(512) void knn_kernel(
    const float* __restrict__ pos, const float4* __restrict__ spk,
    const int* __restrict__ boff, int* __restrict__ nbr)
{
    int wid  = threadIdx.x >> 6;
    int lane = threadIdx.x & 63;
    int row  = blockIdx.x * 8 + wid;          // 0..8191
    int b    = row >> 12;
    int i    = row & 4095;

    const float4* sp = spk + (size_t)b * NNODES;
    const int*    bo = boff + b * (NCELL + 1);

    float2 pr = ((const float2*)(pos + (size_t)b * NNODES * 2))[i];
    float qx = cleanf(pr.x), qy = cleanf(pr.y);
    int qcx = binf(qx), qcy = binf(qy);

    unsigned long long best[8];
    #pragma unroll
    for (int q = 0; q < 8; ++q) best[q] = ~0ull;

    auto sweep = [&](int s0, int s1) {
        for (int p0 = s0; p0 < s1; p0 += 64) {
            int p = p0 + lane;
            bool valid = (p < s1);
            float4 cp = sp[min(p, s1 - 1)];
            int ci = __float_as_int(cp.z);
            float dx = qx - cp.x, dy = qy - cp.y;
            float d2 = __fadd_rn(__fmul_rn(dx, dx), __fmul_rn(dy, dy));
            unsigned long long cur =
                ((unsigned long long)__float_as_uint(d2) << 32) | (unsigned)ci;
            if (!valid || ci == i) cur = ~0ull;
            INSERT8(cur);
        }
    };

    // ---- phase A: widen square (counts only) until >= 9 points ----
    int r = 1, cxL, cxH, cyL, cyH;
    for (;;) {
        cxL = max(qcx - r, 0); cxH = min(qcx + r, GX - 1);
        cyL = max(qcy - r, 0); cyH = min(qcy + r, GX - 1);
        int cnt = 0;
        for (int cy = cyL; cy <= cyH; ++cy)
            cnt += bo[cy * GX + cxH + 1] - bo[cy * GX + cxL];
        if (cnt >= 9 || (cxL == 0 && cxH == GX - 1 && cyL == 0 && cyH == GX - 1))
            break;
        r += (r < 4) ? 1 : (r >> 1);         // geometric growth in tails
    }
    for (int cy = cyL; cy <= cyH; ++cy)
        sweep(bo[cy * GX + cxL], bo[cy * GX + cxH + 1]);

    // ---- extract exact top-8 of phase A (ascending) into m8[] ----
    unsigned long long m8[8];
    #pragma unroll
    for (int rr = 0; rr < 8; ++rr) {
        unsigned long long k = best[0];
        #pragma unroll
        for (int off = 32; off > 0; off >>= 1) {
            unsigned long long o = __shfl_xor(k, off, 64);
            k = (o < k) ? o : k;
        }
        m8[rr] = k;
        if (best[0] == k) {
            #pragma unroll
            for (int q = 0; q < 7; ++q) best[q] = best[q + 1];
            best[7] = ~0ull;
        }
    }

    // window half-width from U = 8th-smallest d2 (finite by construction)
    float U = __uint_as_float((unsigned)(m8[7] >> 32));
    float w = sqrtf(U) * 1.0001f + 1.0e-5f;
    int bxlo = binf(qx - w), bxhi = binf(qx + w);
    int bylo = binf(qy - w), byhi = binf(qy + w);

    // reinit per-lane lists; inject m8[r] into lane r (static-index select)
    #pragma unroll
    for (int q = 0; q < 8; ++q) best[q] = ~0ull;
    unsigned long long inj = m8[0];
    #pragma unroll
    for (int rr = 1; rr < 8; ++rr) inj = (lane == rr) ? m8[rr] : inj;
    if (lane < 8) best[0] = inj;

    // ---- phase B: B-square minus A-square (exact exclusion, no dup keys) ----
    for (int cy = bylo; cy <= byhi; ++cy) {
        int rl = bo[cy * GX + bxlo], rh = bo[cy * GX + bxhi + 1];
        if (cy >= cyL && cy <= cyH) {
            int e = bo[cy * GX + min(cxL, bxhi + 1)];   // left of A-cols
            sweep(rl, e);
            int s = bo[cy * GX + max(cxH + 1, bxlo)];   // right of A-cols
            sweep(s, rh);
        } else {
            sweep(rl, rh);
        }
    }

    // ---- final merge: 8 rounds of butterfly wave-min + pop ----
    unsigned out_j = 0;
    #pragma unroll
    for (int rr = 0; rr < 8; ++rr) {
        unsigned long long k = best[0];
        #pragma unroll
        for (int off = 32; off > 0; off >>= 1) {
            unsigned long long o = __shfl_xor(k, off, 64);
            k = (o < k) ? o : k;
        }
        if (lane == rr) out_j = (unsigned)k;
        if (best[0] == k) {                  // unique keys -> exactly one lane
            #pragma unroll
            for (int q = 0; q < 7; ++q) best[q] = best[q + 1];
            best[7] = ~0ull;
        }
    }
    if (lane < 8) nbr[(size_t)row * KNN + lane] = (int)out_j;
}

// ---------------------------------------------------------------------------
// Kernel 2: fused multipole + msg GEMM, b128-transposed weights.
// Per wave: 4 nodes batched. Weights read as per-lane-column ds_read_b128
// (pad-68 rows: bank-uniform); x operand broadcast via v_readlane (VALU),
// keeping the LDS pipe for weight streaming only. Per-accumulator summation
// order identical to previous version (i ascending, same expression shapes)
// -> bit-identical outputs.
// LDS: 85K Wl + 2x17K W1 halves + 8.3K xsh + csh ~= 128 KB -> 1 block/CU.
// ---------------------------------------------------------------------------
__global__ __launch_bounds__(512) void multipole_gemm_kernel(
    const float* __restrict__ x, const float* __restrict__ pos,
    const float* __restrict__ mWlt, const float* __restrict__ mW1tA,
    const float* __restrict__ mW1tB, const float* __restrict__ osc,
    const float* __restrict__ lns, const float* __restrict__ lnb,
    float* __restrict__ mp, float* __restrict__ ab)
{
    __shared__ alignas(16) float Wl[5 * 64 * 68];   // [o][j][i] pad-68, 85 KB
    __shared__ alignas(16) float WA[64 * 68];       // 17 KB
    __shared__ alignas(16) float WB[64 * 68];       // 17 KB
    __shared__ float xsh[32][65];                   // cleaned x
    __shared__ float csh[32][5];                    // per-node c_o
    int base = blockIdx.x * 32;

    // stage transposed weights: coalesced global float4, conflict-free LDS
    for (int g = threadIdx.x; g < 5 * 64 * 16; g += 512) {
        int oj = g >> 4, i4 = (g & 15) * 4;
        *(float4*)&Wl[oj * 68 + i4] = *(const float4*)&mWlt[oj * 64 + i4];
    }
    for (int g = threadIdx.x; g < 64 * 16; g += 512) {
        int j = g >> 4, i4 = (g & 15) * 4;
        *(float4*)&WA[j * 68 + i4] = *(const float4*)&mW1tA[j * 64 + i4];
        *(float4*)&WB[j * 68 + i4] = *(const float4*)&mW1tB[j * 64 + i4];
    }
    for (int g = threadIdx.x; g < 32 * 64; g += 512)
        xsh[g >> 6][g & 63] = cleanf(x[(size_t)base * 64 + g]);
    __syncthreads();

    if (threadIdx.x < 32) {
        int t = threadIdx.x;
        float ss = 0.0f;
        for (int i = 0; i < 64; ++i) { float v = xsh[t][i]; ss += v * v; }
        float nx = sqrtf(ss);
        int node = base + t;
        float px = cleanf(pos[(size_t)node * 2]);
        float py = cleanf(pos[(size_t)node * 2 + 1]);
        float r = fmaxf(sqrtf(px * px + py * py), 1.0e-8f);
        float th = atan2f(py, px + 1.0e-8f);
        float r2 = r * r, r3 = r2 * r, r4 = r2 * r2;  // lax.integer_pow order
        float ro[5] = {1.0f, r, r2, r3, r4};
        #pragma unroll
        for (int o = 0; o < 5; ++o) {
            float radial = tanhf(ro[o] / (1.0f + ro[o]));
            float ang = cosf((float)o * th);
            float s = radial * ang;
            float denom = fabsf(s) * nx + 1.0e-8f;     // ||s*x|| + EPS
            float sc = fminf(fmaxf(osc[o], 0.01f), 1.0f);
            csh[t][o] = (s / denom) * sc / (float)(o + 1);
        }
    }
    __syncthreads();

    int w = threadIdx.x >> 6;
    int lane = threadIdx.x & 63;
    int nl0 = w * 4;

    // per-node operands live across lanes: lane L holds x[node][L]
    float xc[4], xw[4];
    #pragma unroll
    for (int r_ = 0; r_ < 4; ++r_) {
        xc[r_] = xsh[nl0 + r_][lane];
        xw[r_] = x[(size_t)(base + nl0 + r_) * 64 + lane];   // raw x
    }

    float acc[4][5];
    float accA[4] = {0.f, 0.f, 0.f, 0.f};
    float accB[4] = {0.f, 0.f, 0.f, 0.f};
    #pragma unroll
    for (int r_ = 0; r_ < 4; ++r_)
        #pragma unroll
        for (int o = 0; o < 5; ++o) acc[r_][o] = 0.0f;

    for (int i4 = 0; i4 < 64; i4 += 4) {   // 7 b128 LDS, 32 RL, 112 FMA / iter
        float4 q0 = *(const float4*)&Wl[(0 * 64 + lane) * 68 + i4];
        float4 q1 = *(const float4*)&Wl[(1 * 64 + lane) * 68 + i4];
        float4 q2 = *(const float4*)&Wl[(2 * 64 + lane) * 68 + i4];
        float4 q3 = *(const float4*)&Wl[(3 * 64 + lane) * 68 + i4];
        float4 q4 = *(const float4*)&Wl[(4 * 64 + lane) * 68 + i4];
        float4 qa = *(const float4*)&WA[lane * 68 + i4];
        float4 qb = *(const float4*)&WB[lane * 68 + i4];
        float w0v[4] = {q0.x, q0.y, q0.z, q0.w};
        float w1v[4] = {q1.x, q1.y, q1.z, q1.w};
        float w2v[4] = {q2.x, q2.y, q2.z, q2.w};
        float w3v[4] = {q3.x, q3.y, q3.z, q3.w};
        float w4v[4] = {q4.x, q4.y, q4.z, q4.w};
        float wav[4] = {qa.x, qa.y, qa.z, qa.w};
        float wbv[4] = {qb.x, qb.y, qb.z, qb.w};
        #pragma unroll
        for (int q = 0; q < 4; ++q) {
            #pragma unroll
            for (int r_ = 0; r_ < 4; ++r_) {
                float xi = rdl(xc[r_], i4 + q);
                float xv = rdl(xw[r_], i4 + q);
                acc[r_][0] += xi * w0v[q]; acc[r_][1] += xi * w1v[q];
                acc[r_][2] += xi * w2v[q]; acc[r_][3] += xi * w3v[q];
                acc[r_][4] += xi * w4v[q];
                accA[r_] += xv * wav[q];
                accB[r_] += xv * wbv[q];
            }
        }
    }

    float lnsv = lns[lane], lnbv = lnb[lane];
    #pragma unroll
    for (int r_ = 0; r_ < 4; ++r_) {
        int node = base + nl0 + r_;
        float tv = csh[nl0 + r_][0] * acc[r_][0] + csh[nl0 + r_][1] * acc[r_][1]
                 + csh[nl0 + r_][2] * acc[r_][2] + csh[nl0 + r_][3] * acc[r_][3]
                 + csh[nl0 + r_][4] * acc[r_][4];
        float mu = wave_sum64(tv) * (1.0f / 64.0f);
        float dv = tv - mu;
        float var = wave_sum64(dv * dv) * (1.0f / 64.0f);
        float o_ = dv * (1.0f / sqrtf(var + 1.0e-6f)) * lnsv + lnbv;
        if (o_ != o_) o_ = xsh[nl0 + r_][lane];  // where(isnan, cleaned x)
        mp[(size_t)node * 64 + lane] = o_;
        ab[(size_t)node * 128 + lane]      = accA[r_];
        ab[(size_t)node * 128 + 64 + lane] = accB[r_];
    }
}

// ---------------------------------------------------------------------------
// Kernel 3: fused msg-gather + update MLP + final LayerNorm, b128 weights.
// Per wave: 4 nodes batched through every matvec; activations broadcast via
// v_readlane; weights as per-lane-column b128 (pad-132/68: bank-uniform).
// Accumulation orders identical to previous version -> bit-identical.
// LDS: 66K W1u + 33K W2u + 17K W2m = 116 KB -> 1 block/CU.
// ---------------------------------------------------------------------------
__global__ __launch_bounds__(512) void msg_upd_kernel(
    const float* __restrict__ x, const float* __restrict__ ab,
    const int* __restrict__ nbr, const float* __restrict__ mp,
    const float* __restrict__ mb1, const float* __restrict__ mW2t,
    const float* __restrict__ mb2,
    const float* __restrict__ uW1t, const float* __restrict__ ub1,
    const float* __restrict__ uW2t, const float* __restrict__ ub2,
    const float* __restrict__ lns, const float* __restrict__ lnb,
    float* __restrict__ out)
{
    __shared__ alignas(16) float W1ul[128 * 132];  // [j][i] pad-132, 66 KB
    __shared__ alignas(16) float W2ul[64 * 132];   // [j][h] pad-132, 33 KB
    __shared__ alignas(16) float W2ml[64 * 68];    // [j][h] pad-68, 17 KB

    for (int g = threadIdx.x; g < 128 * 32; g += 512) {
        int j = g >> 5, i4 = (g & 31) * 4;
        *(float4*)&W1ul[j * 132 + i4] = *(const float4*)&uW1t[j * 128 + i4];
    }
    for (int g = threadIdx.x; g < 64 * 32; g += 512) {
        int j = g >> 5, h4 = (g & 31) * 4;
        *(float4*)&W2ul[j * 132 + h4] = *(const float4*)&uW2t[j * 128 + h4];
    }
    for (int g = threadIdx.x; g < 64 * 16; g += 512) {
        int j = g >> 4, h4 = (g & 15) * 4;
        *(float4*)&W2ml[j * 68 + h4] = *(const float4*)&mW2t[j * 64 + h4];
    }
    __syncthreads();

    int w = threadIdx.x >> 6;
    int lane = threadIdx.x & 63;
    float b1m = mb1[lane], b2m = mb2[lane];
    float b1a = ub1[lane], b1b = ub1[lane + 64], b2u = ub2[lane];
    float lnsv = lns[lane], lnbv = lnb[lane];

    int node0 = blockIdx.x * 32 + w * 4;
    const float* abb = ab + (((size_t)(node0 >> 12)) << 12) * 128;  // batch base
    const int* nb = nbr + (size_t)node0 * 8;

    float av[4], uav[4], xv[4], hmr[4];
    #pragma unroll
    for (int r = 0; r < 4; ++r) {
        av[r]  = ab[(size_t)(node0 + r) * 128 + lane];
        uav[r] = mp[(size_t)(node0 + r) * 64 + lane];
        xv[r]  = x[(size_t)(node0 + r) * 64 + lane];
    }

    // ---- gelu/gather phase (pipelined: next node's B-rows under gelu) ----
    float bvc[8];
    #pragma unroll
    for (int k = 0; k < 8; ++k)
        bvc[k] = abb[(size_t)nb[k] * 128 + 64 + lane];
    #pragma unroll
    for (int r = 0; r < 4; ++r) {
        float bvn[8];
        if (r < 3) {
            #pragma unroll
            for (int k = 0; k < 8; ++k)
                bvn[k] = abb[(size_t)nb[8 * (r + 1) + k] * 128 + 64 + lane];
        }
        float hsum = 0.0f;
        #pragma unroll
        for (int k = 0; k < 8; ++k)
            hsum += gelu_tanh(av[r] + bvc[k] + b1m);
        hmr[r] = hsum * 0.125f;
        if (r < 3) {
            #pragma unroll
            for (int k = 0; k < 8; ++k) bvc[k] = bvn[k];
        }
    }

    // ---- msg W2: o_[r] = hm_r @ W2m   (same h-order as before) ----
    float o_[4] = {0.f, 0.f, 0.f, 0.f};
    #pragma unroll
    for (int h4 = 0; h4 < 64; h4 += 4) {
        float4 wq = *(const float4*)&W2ml[lane * 68 + h4];
        #pragma unroll
        for (int r = 0; r < 4; ++r) {
            o_[r] += rdl(hmr[r], h4)     * wq.x + rdl(hmr[r], h4 + 1) * wq.y
                   + rdl(hmr[r], h4 + 2) * wq.z + rdl(hmr[r], h4 + 3) * wq.w;
        }
    }
    float ubv[4];
    #pragma unroll
    for (int r = 0; r < 4; ++r) ubv[r] = o_[r] + b2m;

    // ---- update W1: u = [mp | lm], i ascending across both halves ----
    float h1a[4] = {0.f, 0.f, 0.f, 0.f}, h2a[4] = {0.f, 0.f, 0.f, 0.f};
    #pragma unroll
    for (int i4 = 0; i4 < 64; i4 += 4) {
        float4 w1 = *(const float4*)&W1ul[lane * 132 + i4];
        float4 w2 = *(const float4*)&W1ul[(lane + 64) * 132 + i4];
        #pragma unroll
        for (int r = 0; r < 4; ++r) {
            float u0 = rdl(uav[r], i4),     u1 = rdl(uav[r], i4 + 1),
                  u2 = rdl(uav[r], i4 + 2), u3 = rdl(uav[r], i4 + 3);
            h1a[r] += u0 * w1.x + u1 * w1.y + u2 * w1.z + u3 * w1.w;
            h2a[r] += u0 * w2.x + u1 * w2.y + u2 * w2.z + u3 * w2.w;
        }
    }
    #pragma unroll
    for (int i4 = 0; i4 < 64; i4 += 4) {
        float4 w1 = *(const float4*)&W1ul[lane * 132 + 64 + i4];
        float4 w2 = *(const float4*)&W1ul[(lane + 64) * 132 + 64 + i4];
        #pragma unroll
        for (int r = 0; r < 4; ++r) {
            float u0 = rdl(ubv[r], i4),     u1 = rdl(ubv[r], i4 + 1),
                  u2 = rdl(ubv[r], i4 + 2), u3 = rdl(ubv[r], i4 + 3);
            h1a[r] += u0 * w1.x + u1 * w1.y + u2 * w1.z + u3 * w1.w;
            h2a[r] += u0 * w2.x + u1 * w2.y + u2 * w2.z + u3 * w2.w;
        }
    }

    float hla[4], hlb[4], accq[4];
    #pragma unroll
    for (int r = 0; r < 4; ++r) {
        hla[r] = gelu_tanh(h1a[r] + b1a);
        hlb[r] = gelu_tanh(h2a[r] + b1b);
        accq[r] = 0.f;
    }

    // ---- update W2: h ascending across both halves ----
    #pragma unroll
    for (int h4 = 0; h4 < 64; h4 += 4) {
        float4 wq = *(const float4*)&W2ul[lane * 132 + h4];
        #pragma unroll
        for (int r = 0; r < 4; ++r) {
            accq[r] += rdl(hla[r], h4)     * wq.x + rdl(hla[r], h4 + 1) * wq.y
                     + rdl(hla[r], h4 + 2) * wq.z + rdl(hla[r], h4 + 3) * wq.w;
        }
    }
    #pragma unroll
    for (int h4 = 0; h4 < 64; h4 += 4) {
        float4 wq = *(const float4*)&W2ul[lane * 132 + 64 + h4];
        #pragma unroll
        for (int r = 0; r < 4; ++r) {
            accq[r] += rdl(hlb[r], h4)     * wq.x + rdl(hlb[r], h4 + 1) * wq.y
                     + rdl(hlb[r], h4 + 2) * wq.z + rdl(hlb[r], h4 + 3) * wq.w;
        }
    }

    // ---- residual + LayerNorm ----
    #pragma unroll
    for (int r = 0; r < 4; ++r) {
        float pre = xv[r] + accq[r] + b2u;
        float mu = wave_sum64(pre) * (1.0f / 64.0f);
        float dv = pre - mu;
        float var = wave_sum64(dv * dv) * (1.0f / 64.0f);
        out[(size_t)(node0 + r) * 64 + lane] =
            dv * (1.0f / sqrtf(var + 1.0e-6f)) * lnsv + lnbv;
    }
}

extern "C" void kernel_launch(void* const* d_in, const int* in_sizes, int n_in,
                              void* d_out, int out_size, void* d_ws, size_t ws_size,
                              hipStream_t stream)
{
    (void)in_sizes; (void)n_in; (void)out_size; (void)ws_size;
    const float* x     = (const float*)d_in[0];
    const float* pos   = (const float*)d_in[1];
    const float* mw    = (const float*)d_in[2];
    const float* osc   = (const float*)d_in[3];
    const float* mplns = (const float*)d_in[4];
    const float* mplnb = (const float*)d_in[5];
    const float* mW1   = (const float*)d_in[6];
    const float* mb1   = (const float*)d_in[7];
    const float* mW2   = (const float*)d_in[8];
    const float* mb2   = (const float*)d_in[9];
    const float* uW1   = (const float*)d_in[10];
    const float* ub1   = (const float*)d_in[11];
    const float* uW2   = (const float*)d_in[12];
    const float* ub2   = (const float*)d_in[13];
    const float* olns  = (const float*)d_in[14];
    const float* olnb  = (const float*)d_in[15];
    float* out = (float*)d_out;

    // ws layout:
    //   nbr 256K | mp 2M | ab 4M | spk 128K | boff 33K |
    //   uW1t 64K | uW2t 32K | mW2t 16K | mWlt 80K | mW1tA 16K | mW1tB 16K
    char* ws = (char*)d_ws;
    int*    nbr   = (int*)ws;
    float*  mp    = (float*)(ws + 262144);
    float*  ab    = (float*)(ws + 2359296);
    float4* spk   = (float4*)(ws + 6553600);
    int*    boff  = (int*)(ws + 6684672);
    float*  uW1t  = (float*)(ws + 6717696);
    float*  uW2t  = (float*)(ws + 6783232);
    float*  mW2t  = (float*)(ws + 6816000);
    float*  mWlt  = (float*)(ws + 6832384);
    float*  mW1tA = (float*)(ws + 6914304);
    float*  mW1tB = (float*)(ws + 6930688);

    prep_kernel<<<8, 1024, 0, stream>>>(pos, spk, boff,
        mw, mW1, mW2, uW1, uW2, uW1t, uW2t, mW2t, mWlt, mW1tA, mW1tB);
    knn_kernel<<<1024, 512, 0, stream>>>(pos, spk, boff, nbr);
    multipole_gemm_kernel<<<256, 512, 0, stream>>>(
        x, pos, mWlt, mW1tA, mW1tB, osc, mplns, mplnb, mp, ab);
    msg_upd_kernel<<<256, 512, 0, stream>>>(
        x, ab, nbr, mp, mb1, mW2t, mb2, uW1t, ub1, uW2t, ub2, olns, olnb, out);
}